// Round 7
// baseline (725.083 us; speedup 1.0000x reference)
//
#include <hip/hip_runtime.h>
#include <stdint.h>

#define DEVI __device__ __forceinline__

typedef __bf16 bf16x8 __attribute__((ext_vector_type(8)));
typedef float  floatx4 __attribute__((ext_vector_type(4)));

// B=8, S=2048, H=1024. M = B*S = 16384.
// ws: Q @0 (32MiB, pre-scaled log2e/32) | K @+32M | Vt @+64M ([8][1024 d][2048 k])
//     lvec @+96M (f32[16384]) | P @+96M+64K (bf16 [8][2048][2048]);
//     P region overlays Xb (32MiB) + Wt (6MiB), dead before P written.
//
// Round-11: READ-AHEAD pipeline. All prior variants had frag ds_reads in the
// SAME phase as their consuming MFMAs -> LDS service and MFMA issue alternate
// chip-wide (serialized floor ~4400cy/tile, measured 6500). Now phase K
// issues the reads for phase K+1 AFTER its MFMA cluster; service hides under
// the 16-MFMA pipe time. 1 barrier/phase (4/tile).
//
// Phase map (tile t, quadrants (MH,NH)):
//   p1: MFMA(0,0)=af0xb0 ; stage AH1(t+1)->bn ; read b1(t)    [4 ds]
//   p2: MFMA(0,1)=af0xb1 ; stage BH1(t+1)->bn ; read af1(t)   [8 ds] ; V6
//   p3: MFMA(1,1)=af1xb1 ; stage AH0(t+2)->bc ; read af0(t+1) [8 ds] ; V6
//   p4: MFMA(1,0)=af1xb0 ; stage BH0(t+2)->bc ; read b0n(t+1) [4 ds] ; V4
// Ledger (steady, 2 loads/stage): enter t with O=4 {AH0,BH0}(t+1).
//   p1 +2 -> 6 (no wait).  p2 +2 -> 8, V6 retires AH0(t+1) [read@p3] -> 6.
//   p3 +2 -> 8, V6 retires BH0(t+1) [read@p4] -> 6.
//   p4 +2 -> 8, V4 retires {AH1,BH1}(t+1) [reads @p2(t+1),p1(t+1)] -> 4. ✓
// Tails: s2=false -> p3-end V0 (drains {AH1,BH1,BH0}(kI-1) before their
// reads), p4-end skip; last tile issues no stages, nothing in flight.
// WAR (LDS): each stage targets a region whose last read was issued >=2
// phases earlier and completed at the intervening LGK0 (checked per-region).
// WAR (regs): b0 read@p4 into b0n, rotated at tile end; af0 overwritten @p3
// (dead since p2-MFMA); af1/b1 rewritten next tile after last use.
// Register budget (unified 256/wave at 8 waves/CU): acc 128 + frag peak 96
// (p2: af0+af1+b0+b1) + lane offsets/temps ~20 -> ~245. Persistent stage
// streams DELETED (addresses recomputed inline, transient) to pay for the
// deeper frag liveness.
// (Kept: no 32x32 MFMA, no LDS-staged epilogue, no B-direct loads; Q carries
// log2e/32 so EPI2 uses raw v_exp_f32.)

DEVI unsigned short f2bf(float f) {
  union { float f; uint32_t u; } x; x.f = f;
  return (unsigned short)((x.u + 0x7fffu + ((x.u >> 16) & 1u)) >> 16);
}
DEVI float bf2f(unsigned short s) {
  union { uint32_t u; float f; } x; x.u = ((uint32_t)s) << 16;
  return x.f;
}

// ---------------- fused prep: X->bf16, 3x W transpose->bf16, lvec=0 ----------------
__global__ __launch_bounds__(256) void k_prep(
    const float* __restrict__ X, unsigned short* __restrict__ Xb,
    const float* __restrict__ Wq, const float* __restrict__ Wk,
    const float* __restrict__ Wv, unsigned short* __restrict__ Wt,
    float* __restrict__ lvec) {
  __shared__ float tile[64][65];
  int bx = blockIdx.x, t = threadIdx.x;
  if (bx < 16384) {                 // convert X: 4194304 float4 groups
    int i = bx * 256 + t;
    float4 v = ((const float4*)X)[i];
    ushort4 o;
    o.x = f2bf(v.x); o.y = f2bf(v.y); o.z = f2bf(v.z); o.w = f2bf(v.w);
    ((ushort4*)Xb)[i] = o;
  } else if (bx < 17152) {          // 3 x 256 transpose blocks
    int idx = bx - 16384;
    int sel = idx >> 8, b2 = idx & 255;
    const float* W = sel == 0 ? Wq : (sel == 1 ? Wk : Wv);
    unsigned short* Wo = Wt + ((size_t)sel << 20);
    int h0 = (b2 & 15) * 64, d0 = (b2 >> 4) * 64;
#pragma unroll
    for (int i = 0; i < 16; ++i) {
      int idx2 = i * 256 + t; int r = idx2 >> 6, c = idx2 & 63;
      tile[r][c] = W[(size_t)(h0 + r) * 1024 + d0 + c];
    }
    __syncthreads();
#pragma unroll
    for (int i = 0; i < 16; ++i) {
      int idx2 = i * 256 + t; int r = idx2 >> 6, c = idx2 & 63;
      Wo[(size_t)(d0 + r) * 1024 + h0 + c] = f2bf(tile[c][r]);
    }
  } else {                          // zero lvec (16384 f32)
    float4 z4 = {0.f, 0.f, 0.f, 0.f};
#pragma unroll
    for (int i = 0; i < 16; ++i) ((float4*)lvec)[i * 256 + t] = z4;
  }
}

// ---------------- async 16B global -> LDS ----------------
DEVI void gl_lds16(const unsigned short* gp, const unsigned short* lp) {
  __builtin_amdgcn_global_load_lds(
      (const __attribute__((address_space(1))) void*)gp,
      (__attribute__((address_space(3))) void*)lp, 16, 0, 0);
}

// Stage one half-tile (2 gl_lds / thread). Addresses computed inline
// (transient VALU; no persistent streams -> register headroom for frags).
// A halves (q): rows m0 + (slot>>3)*128 + q*64 + (slot&7)*8 + lr
// B halves (q): rows n0 + (slot>>2)*64 + q*32 + (slot&3)*8 + lr
#define STAGE_A(q, BUF, KT)                                                   \
  _Pragma("unroll") for (int j = 0; j < 2; ++j) {                             \
    const int slot = w * 2 + j;                                               \
    const int rA = (slot >> 3) * 128 + (q) * 64 + (slot & 7) * 8;             \
    gl_lds16((const unsigned short*)(AzByte +                                 \
             (size_t)(unsigned)((m0 + rA) * ldA) * 2 + (KT) * 128 + laneA),   \
             AsF + (BUF) + rA * 64);                                          \
  }
#define STAGE_B(q, BUF, KT)                                                   \
  _Pragma("unroll") for (int j = 0; j < 2; ++j) {                             \
    const int slot = w * 2 + j;                                               \
    const int rB = (slot >> 2) * 64 + (q) * 32 + (slot & 3) * 8;              \
    gl_lds16((const unsigned short*)(BzByte +                                 \
             (size_t)(unsigned)((n0 + rB) * ldB) * 2 + (KT) * 128 + laneB),   \
             BsF + (BUF) + rB * 64);                                          \
  }

// Fragment loads: base ptr + compile-time immediate only.
#define READ_AF(dst, bp0, bp1, MH)                                            \
  _Pragma("unroll") for (int ms = 0; ms < 4; ++ms) {                          \
    dst[0][ms] = *(const bf16x8*)((bp0) + (MH) * 8192 + ms * 2048);           \
    dst[1][ms] = *(const bf16x8*)((bp1) + (MH) * 8192 + ms * 2048);           \
  }
#define READ_BF(dst, bp0, bp1, NH)                                            \
  _Pragma("unroll") for (int ns = 0; ns < 2; ++ns) {                          \
    dst[0][ns] = *(const bf16x8*)((bp0) + (NH) * 4096 + ns * 2048);           \
    dst[1][ns] = *(const bf16x8*)((bp1) + (NH) * 4096 + ns * 2048);           \
  }

// 16 MFMAs for one C-quadrant.
#define MFMA_Q(ASET, BSET, MH, NH)                                            \
  _Pragma("unroll") for (int kk = 0; kk < 2; ++kk)                            \
  _Pragma("unroll") for (int ms = 0; ms < 4; ++ms)                            \
  _Pragma("unroll") for (int ns = 0; ns < 2; ++ns)                            \
    acc[(MH) * 4 + ms][(NH) * 2 + ns] =                                       \
        __builtin_amdgcn_mfma_f32_16x16x32_bf16(                              \
            ASET[kk][ms], BSET[kk][ns], acc[(MH) * 4 + ms][(NH) * 2 + ns],    \
            0, 0, 0);

#define PRIO1 __builtin_amdgcn_s_setprio(1)
#define PRIO0 __builtin_amdgcn_s_setprio(0)
#define WAITV6 asm volatile("s_waitcnt vmcnt(6)" ::: "memory")
#define WAITV4 asm volatile("s_waitcnt vmcnt(4)" ::: "memory")
#define WAITV0 asm volatile("s_waitcnt vmcnt(0)" ::: "memory")
#define SBAR __builtin_amdgcn_s_barrier()
#define FENCE __builtin_amdgcn_sched_barrier(0)
// Coarse post-barrier wait (rule #18: fence after the wait).
#define LGK0                                                                  \
  do {                                                                        \
    asm volatile("s_waitcnt lgkmcnt(0)" ::: "memory");                        \
    __builtin_amdgcn_sched_barrier(0);                                        \
  } while (0)

// ---------------- C = A * Bt^T  (both bf16 row-major, K-major rows) ----------------
// 256x256 tile, BK=64, 8 waves (2M x 4N, 128x64 each), 128KiB dbuf LDS.
// EPI: 4 = fused QKV (sel=blockIdx.y>>2): Q (x+b)*log2e/32, K x+b, V -> Vt[b][d][k]
//      2 = P = 2^S masked, bf16; atomic row sums -> lsum
//      3 = O = (P*V) * 1/lvec[row], f32
template <int EPI>
__global__ __launch_bounds__(512, 2) void k_gemm(
    const unsigned short* __restrict__ A, const unsigned short* __restrict__ Bt,
    void* __restrict__ Cv,
    const float* __restrict__ bias_q, const float* __restrict__ bias_k,
    const float* __restrict__ bias_v,
    const float* __restrict__ lvec, float* __restrict__ lsum,
    const int* __restrict__ mask,
    long aZ, long bZ, int ldA, int ldB, int kIters)
{
  // One buffer = 256x64 bf16 = 16384 ushorts (32KB); dbuf per operand.
  __shared__ __attribute__((aligned(16))) unsigned short AsF[2 * 256 * 64];
  __shared__ __attribute__((aligned(16))) unsigned short BsF[2 * 256 * 64];
  const int tid = threadIdx.x, w = tid >> 6, l = tid & 63;
  const int quad = l >> 4, l15 = l & 15;
  const int wr = w & 1, wc = w >> 1;           // 2M x 4N wave grid
  const int wm = wr * 128, wn = wc * 64;
  const int m0 = blockIdx.x * 256;
  const int z = blockIdx.z;

  int n0, sel = 0;
  if constexpr (EPI == 4) { sel = blockIdx.y >> 2; n0 = (blockIdx.y & 3) * 256; }
  else n0 = blockIdx.y * 256;

  const unsigned short* Az = A + (size_t)z * aZ;
  const unsigned short* Bz = (EPI == 4) ? (Bt + ((size_t)sel << 20))
                                        : (Bt + (size_t)z * bZ);
  const char* AzByte = (const char*)Az;
  const char* BzByte = (const char*)Bz;

  // per-lane stage byte offsets (stage swizzle u=(l&7)^(l>>3); rows %8==0)
  const int lr = l >> 3, uu = (l & 7) ^ lr;
  const int laneA = (lr * ldA + uu * 8) * 2;
  const int laneB = (lr * ldB + uu * 8) * 2;

  // hoisted fragment-read byte offsets (frag swizzle (rr&7)==l15&7)
  const int cc0 = quad ^ (l15 & 7), cc1 = cc0 ^ 4;
  const int aoffA0 = (wm + l15) * 128 + cc0 * 16;
  const int aoffA1 = (wm + l15) * 128 + cc1 * 16;
  const int aoffB0 = (wn + l15) * 128 + cc0 * 16;
  const int aoffB1 = (wn + l15) * 128 + cc1 * 16;

  floatx4 acc[8][4];
#pragma unroll
  for (int i = 0; i < 8; ++i)
#pragma unroll
    for (int j = 0; j < 4; ++j) { floatx4 zz = {0.f, 0.f, 0.f, 0.f}; acc[i][j] = zz; }

  // -------- prologue: tile0 full + AH0/BH0(1); pre-read af0(0), b0(0) ------
  STAGE_A(0, 0, 0); STAGE_B(0, 0, 0);
  STAGE_A(1, 0, 0); STAGE_B(1, 0, 0);
  if (kIters > 1) {
    STAGE_A(0, 16384, 1); STAGE_B(0, 16384, 1);
    WAITV4;                                 // retires all 8 tile-0 loads
  } else {
    WAITV0;
  }
  SBAR;

  bf16x8 af0[2][4], af1[2][4], b0[2][2], b1[2][2], b0n[2][2];
  {
    const char* cA0 = (const char*)AsF + aoffA0;
    const char* cA1 = (const char*)AsF + aoffA1;
    const char* cB0 = (const char*)BsF + aoffB0;
    const char* cB1 = (const char*)BsF + aoffB1;
    READ_AF(af0, cA0, cA1, 0);
    READ_BF(b0,  cB0, cB1, 0);
  }

  // -------- main loop: 4 read-ahead phases/K-tile, 1 barrier each ----------
#pragma unroll 2
  for (int kt = 0; kt < kIters; ++kt) {
    const int ob = (kt & 1) ? 16384 : 0;
    const int on = ob ^ 16384;
    const char* cA0 = (const char*)(AsF + ob) + aoffA0;
    const char* cA1 = (const char*)(AsF + ob) + aoffA1;
    const char* cB0 = (const char*)(BsF + ob) + aoffB0;
    const char* cB1 = (const char*)(BsF + ob) + aoffB1;
    const char* nA0 = (const char*)(AsF + on) + aoffA0;
    const char* nA1 = (const char*)(AsF + on) + aoffA1;
    const char* nB0 = (const char*)(BsF + on) + aoffB0;
    const char* nB1 = (const char*)(BsF + on) + aoffB1;
    const bool s1 = kt + 1 < kIters, s2 = kt + 2 < kIters;

    // p1: MFMA(0,0); stage AH1(t+1); read b1(t). no vmcnt.
    SBAR; LGK0;
    if (s1) STAGE_A(1, on, kt + 1);
    READ_BF(b1, cB0, cB1, 1);
    FENCE;
    PRIO1; MFMA_Q(af0, b0, 0, 0); PRIO0;

    // p2: MFMA(0,1); stage BH1(t+1); read af1(t); V6 -> AH0(t+1) retired.
    SBAR; LGK0;
    if (s1) STAGE_B(1, on, kt + 1);
    READ_AF(af1, cA0, cA1, 1);
    FENCE;
    PRIO1; MFMA_Q(af0, b1, 0, 1); PRIO0;
    if (s1) WAITV6;

    // p3: MFMA(1,1); stage AH0(t+2); read af0(t+1); V6 -> BH0(t+1) retired.
    SBAR; LGK0;
    if (s2) STAGE_A(0, ob, kt + 2);
    if (s1) READ_AF(af0, nA0, nA1, 0);
    FENCE;
    PRIO1; MFMA_Q(af1, b1, 1, 1); PRIO0;
    if (s2) { WAITV6; } else if (s1) { WAITV0; }

    // p4: MFMA(1,0); stage BH0(t+2); read b0n(t+1); V4 -> {AH1,BH1}(t+1).
    SBAR; LGK0;
    if (s2) STAGE_B(0, ob, kt + 2);
    if (s1) READ_BF(b0n, nB0, nB1, 0);
    FENCE;
    PRIO1; MFMA_Q(af1, b0, 1, 0); PRIO0;
    if (s2) WAITV4;

    if (s1) {
      b0[0][0] = b0n[0][0]; b0[0][1] = b0n[0][1];
      b0[1][0] = b0n[1][0]; b0[1][1] = b0n[1][1];
    }
  }

  // epilogue: C/D layout col = lane&15, row = quad*4 + reg  [m89/m91]
  if constexpr (EPI == 4) {
    unsigned short* C = (unsigned short*)Cv + ((size_t)sel << 24);
    const float* bs = sel == 0 ? bias_q : (sel == 1 ? bias_k : bias_v);
    if (sel < 2) {
      // Q scale folds 1/sqrt(H)=1/32 AND log2(e) so EPI2 uses raw v_exp_f32.
      float sc = sel == 0 ? 0.045084439f : 1.0f;   // log2e/32
#pragma unroll
      for (int ns = 0; ns < 4; ++ns) {
        int n_g = n0 + wn + ns * 16 + l15;
        float bv = bs[n_g];
#pragma unroll
        for (int ms = 0; ms < 8; ++ms) {
          int mb = m0 + wm + ms * 16 + quad * 4;
#pragma unroll
          for (int r = 0; r < 4; ++r)
            C[(size_t)(mb + r) * 1024 + n_g] = f2bf((acc[ms][ns][r] + bv) * sc);
        }
      }
    } else {
      // V -> Vt[b][d][k]: the 4 r-values are CONSECUTIVE in k -> pack 8B stores
#pragma unroll
      for (int ns = 0; ns < 4; ++ns) {
        int n_g = n0 + wn + ns * 16 + l15;
        float bv = bs[n_g];
#pragma unroll
        for (int ms = 0; ms < 8; ++ms) {
          int m_g = m0 + wm + ms * 16 + quad * 4;   // r=0 element
          int bb = m_g >> 11, key = m_g & 2047;
          ushort4 pk;
          pk.x = f2bf(acc[ms][ns][0] + bv);
          pk.y = f2bf(acc[ms][ns][1] + bv);
          pk.z = f2bf(acc[ms][ns][2] + bv);
          pk.w = f2bf(acc[ms][ns][3] + bv);
          *(ushort4*)&C[((size_t)bb << 21) + ((size_t)n_g << 11) + key] = pk;
        }
      }
    }
  } else if constexpr (EPI == 2) {
    // P = 2^S (S pre-scaled by log2e; max-free: |S| small), masked; rowsums
    unsigned short* C = (unsigned short*)Cv + (size_t)z * 4194304;
    const int* mz = mask + z * 2048;
    float rowsum[8][4];
#pragma unroll
    for (int ms = 0; ms < 8; ++ms)
#pragma unroll
      for (int r = 0; r < 4; ++r) rowsum[ms][r] = 0.f;
#pragma unroll
    for (int ns = 0; ns < 4; ++ns) {
      int n_g = n0 + wn + ns * 16 + l15;
      int mv = mz[n_g];
#pragma unroll
      for (int ms = 0; ms < 8; ++ms) {
#pragma unroll
        for (int r = 0; r < 4; ++r) {
          int m_g = m0 + wm + ms * 16 + quad * 4 + r;
          float e;
          asm("v_exp_f32 %0, %1" : "=v"(e) : "v"(acc[ms][ns][r]));  // 2^x
          e = mv ? e : 0.f;
          unsigned short pb = f2bf(e);
          C[(size_t)m_g * 2048 + n_g] = pb;
          rowsum[ms][r] += bf2f(pb);
        }
      }
    }
#pragma unroll
    for (int ms = 0; ms < 8; ++ms) {
#pragma unroll
      for (int r = 0; r < 4; ++r) {
        float s = rowsum[ms][r];
#pragma unroll
        for (int off = 1; off < 16; off <<= 1) s += __shfl_xor(s, off);
        if (l15 == 0) {
          int m_g = m0 + wm + ms * 16 + quad * 4 + r;
          atomicAdd(&lsum[z * 2048 + m_g], s);
        }
      }
    }
  } else {  // EPI == 3: O = (P*V)/l
    float* C = (float*)Cv + (size_t)z * 2048 * 1024;
    const float* lz = lvec + z * 2048;
#pragma unroll
    for (int ms = 0; ms < 8; ++ms) {
#pragma unroll
      for (int r = 0; r < 4; ++r) {
        int m_g = m0 + wm + ms * 16 + quad * 4 + r;
        float lw = lz[m_g];
        float inv = lw > 0.f ? 1.f / lw : 0.f;
#pragma unroll
        for (int ns = 0; ns < 4; ++ns) {
          int n_g = n0 + wn + ns * 16 + l15;
          C[(size_t)m_g * 1024 + n_g] = acc[ms][ns][r] * inv;
        }
      }
    }
  }
}

extern "C" void kernel_launch(void* const* d_in, const int* in_sizes, int n_in,
                              void* d_out, int out_size, void* d_ws, size_t ws_size,
                              hipStream_t stream) {
  const float* X    = (const float*)d_in[0];
  const int*   mask = (const int*)d_in[1];
  const float* Wq   = (const float*)d_in[2];
  const float* bq   = (const float*)d_in[3];
  const float* Wk   = (const float*)d_in[4];
  const float* bk   = (const float*)d_in[5];
  const float* Wv   = (const float*)d_in[6];
  const float* bv   = (const float*)d_in[7];
  float* out = (float*)d_out;

  constexpr size_t SZ = (size_t)16384 * 1024;
  unsigned short* Q    = (unsigned short*)d_ws;      // Q|K|Vt contiguous (sel<<24)
  float*          lvec = (float*)(Q + 3 * SZ);
  unsigned short* P    = (unsigned short*)(lvec + 16384);
  unsigned short* Xb   = P;               // overlaid: dead before P written
  unsigned short* Wt   = Xb + SZ;         // 3 x [1024][1024] bf16
  unsigned short* Vt   = Q + 2 * SZ;

  // 1. prep: X->bf16, W->Wt (bf16, transposed), lvec=0
  k_prep<<<dim3(17153), 256, 0, stream>>>(X, Xb, Wq, Wk, Wv, Wt, lvec);

  // 2. fused QKV projection (12 n-strips: 4 Q, 4 K, 4 V)
  k_gemm<4><<<dim3(64, 12, 1), 512, 0, stream>>>(
      Xb, Wt, (void*)Q, bq, bk, bv, nullptr, nullptr, nullptr,
      0, 0, 1024, 1024, 16);

  // 3. P = 2^(Q K^T * log2e/32) masked + atomic row sums
  k_gemm<2><<<dim3(8, 8, 8), 512, 0, stream>>>(
      Q, Q + SZ, (void*)P, nullptr, nullptr, nullptr, nullptr, lvec, mask,
      2048 * 1024, 2048 * 1024, 1024, 1024, 16);

  // 4. O = (P V) / l  -> fp32 out
  k_gemm<3><<<dim3(8, 4, 8), 512, 0, stream>>>(
      P, Vt, (void*)out, nullptr, nullptr, nullptr, lvec, nullptr, nullptr,
      2048 * 2048, 1024 * 2048, 2048, 2048, 32);
}

// Round 9
// 378.469 us; speedup vs baseline: 1.9158x; 1.9158x over previous
//
#include <hip/hip_runtime.h>
#include <stdint.h>

#define DEVI __device__ __forceinline__

typedef __bf16 bf16x8 __attribute__((ext_vector_type(8)));
typedef float  floatx4 __attribute__((ext_vector_type(4)));

// B=8, S=2048, H=1024. M = B*S = 16384.
// ws: Q @0 (32MiB, pre-scaled log2e/32) | K @+32M | Vt @+64M ([8][1024 d][2048 k])
//     lvec @+96M (f32[16384]) | P @+96M+64K (bf16 [8][2048][2048]);
//     P region overlays Xb (32MiB) + Wt (6MiB), dead before P written.
//
// Round-14 = round-8 resubmit (infra failure, not kernel) with one safety
// fix: single contiguous LDS block (LDSu) instead of separate AsF/BsF arrays,
// so the wave-slice epilogue (w*8192 spans 128KB) is provably in-bounds
// rather than relying on allocation order.
// Content = round-5 base (401.8us best; 2 merged phases/K-tile, persistent
// streams, vmcnt(4)@P34 — K-loop UNTOUCHED) + two loop-invariant fixes:
//  (1) LDS-restaged packed epilogues (Q/K, Vt, P): after the final barrier
//      LDS is dead (last-tile reads lgkm-gated before final SBAR); each wave
//      round-trips its 16KB output slice (LDSu + w*8192) scalar-ds_write ->
//      b128 read -> 16B coalesced global stores. Kills ~2x write
//      amplification (WRITE_SIZE 166MB vs 96/64 ideal).
//  (2) Bijective rect XCD swizzle for EPI2 (4x2 rects/z) and EPI3 (2x2):
//      co-locates panel sharers per XCD L2 (EPI2 L3 traffic 288->192MB).
//      Bijectivity: bit-permutation maps (verified per-bit in r8 notes).
// r6/r7 lessons: do not touch phases/waits; no extra cross-phase register
// liveness (spills at acc128+frag96).
// (Kept: no 32x32 MFMA, no B-direct loads; Q carries log2e/32 -> v_exp_f32.)

DEVI unsigned short f2bf(float f) {
  union { float f; uint32_t u; } x; x.f = f;
  return (unsigned short)((x.u + 0x7fffu + ((x.u >> 16) & 1u)) >> 16);
}
DEVI float bf2f(unsigned short s) {
  union { uint32_t u; float f; } x; x.u = ((uint32_t)s) << 16;
  return x.f;
}

// ---------------- fused prep: X->bf16, 3x W transpose->bf16, lvec=0 ----------------
__global__ __launch_bounds__(256) void k_prep(
    const float* __restrict__ X, unsigned short* __restrict__ Xb,
    const float* __restrict__ Wq, const float* __restrict__ Wk,
    const float* __restrict__ Wv, unsigned short* __restrict__ Wt,
    float* __restrict__ lvec) {
  __shared__ float tile[64][65];
  int bx = blockIdx.x, t = threadIdx.x;
  if (bx < 16384) {                 // convert X: 4194304 float4 groups
    int i = bx * 256 + t;
    float4 v = ((const float4*)X)[i];
    ushort4 o;
    o.x = f2bf(v.x); o.y = f2bf(v.y); o.z = f2bf(v.z); o.w = f2bf(v.w);
    ((ushort4*)Xb)[i] = o;
  } else if (bx < 17152) {          // 3 x 256 transpose blocks
    int idx = bx - 16384;
    int sel = idx >> 8, b2 = idx & 255;
    const float* W = sel == 0 ? Wq : (sel == 1 ? Wk : Wv);
    unsigned short* Wo = Wt + ((size_t)sel << 20);
    int h0 = (b2 & 15) * 64, d0 = (b2 >> 4) * 64;
#pragma unroll
    for (int i = 0; i < 16; ++i) {
      int idx2 = i * 256 + t; int r = idx2 >> 6, c = idx2 & 63;
      tile[r][c] = W[(size_t)(h0 + r) * 1024 + d0 + c];
    }
    __syncthreads();
#pragma unroll
    for (int i = 0; i < 16; ++i) {
      int idx2 = i * 256 + t; int r = idx2 >> 6, c = idx2 & 63;
      Wo[(size_t)(d0 + r) * 1024 + h0 + c] = f2bf(tile[c][r]);
    }
  } else {                          // zero lvec (16384 f32)
    float4 z4 = {0.f, 0.f, 0.f, 0.f};
#pragma unroll
    for (int i = 0; i < 16; ++i) ((float4*)lvec)[i * 256 + t] = z4;
  }
}

// ---------------- async 16B global -> LDS ----------------
DEVI void gl_lds16(const unsigned short* gp, const unsigned short* lp) {
  __builtin_amdgcn_global_load_lds(
      (const __attribute__((address_space(1))) void*)gp,
      (__attribute__((address_space(3))) void*)lp, 16, 0, 0);
}

// Stage one half-tile from persistent streams; advance streams +128B (+1 K-tile).
// gX[q][j]: fully swizzled per-lane global addr; dX[q][j]: wave-uniform LDS
// ushort offset within a buffer. BUF = buffer base (0 or 16384 ushorts).
#define STAGE_A(q, BUF)                                                       \
  do {                                                                        \
    gl_lds16(gA[q][0], AsF + (BUF) + dA[q][0]);                               \
    gl_lds16(gA[q][1], AsF + (BUF) + dA[q][1]);                               \
    gA[q][0] += 64; gA[q][1] += 64;                                           \
  } while (0)
#define STAGE_B(q, BUF)                                                       \
  do {                                                                        \
    gl_lds16(gB[q][0], BsF + (BUF) + dB[q][0]);                               \
    gl_lds16(gB[q][1], BsF + (BUF) + dB[q][1]);                               \
    gB[q][0] += 64; gB[q][1] += 64;                                           \
  } while (0)

// Fragment loads: base ptr + compile-time immediate only.
#define READ_A(MH)                                                            \
  _Pragma("unroll") for (int ms = 0; ms < 4; ++ms) {                          \
    af[0][ms] = *(const bf16x8*)(pA0 + (MH) * 8192 + ms * 2048);              \
    af[1][ms] = *(const bf16x8*)(pA1 + (MH) * 8192 + ms * 2048);              \
  }
#define READ_B(DST, NH)                                                       \
  _Pragma("unroll") for (int ns = 0; ns < 2; ++ns) {                          \
    DST[0][ns] = *(const bf16x8*)(pB0 + (NH) * 4096 + ns * 2048);             \
    DST[1][ns] = *(const bf16x8*)(pB1 + (NH) * 4096 + ns * 2048);             \
  }

// 16 MFMAs for one C-quadrant (no setprio; caller wraps the cluster).
#define MFMA_Q(MH, NH, BSET)                                                  \
  _Pragma("unroll") for (int kk = 0; kk < 2; ++kk)                            \
  _Pragma("unroll") for (int ms = 0; ms < 4; ++ms)                            \
  _Pragma("unroll") for (int ns = 0; ns < 2; ++ns)                            \
    acc[(MH) * 4 + ms][(NH) * 2 + ns] =                                       \
        __builtin_amdgcn_mfma_f32_16x16x32_bf16(                              \
            af[kk][ms], BSET[kk][ns], acc[(MH) * 4 + ms][(NH) * 2 + ns],      \
            0, 0, 0);

#define PRIO1 __builtin_amdgcn_s_setprio(1)
#define PRIO0 __builtin_amdgcn_s_setprio(0)
#define WAITV4 asm volatile("s_waitcnt vmcnt(4)" ::: "memory")
#define WAITV0 asm volatile("s_waitcnt vmcnt(0)" ::: "memory")
#define SBAR __builtin_amdgcn_s_barrier()

// ---------------- C = A * Bt^T  (both bf16 row-major, K-major rows) ----------------
// 256x256 tile, BK=64, 8 waves (2M x 4N, 128x64 each), 128KiB dbuf LDS.
// EPI: 4 = fused QKV (sel=blockIdx.y>>2): Q (x+b)*log2e/32, K x+b, V -> Vt[b][d][k]
//      2 = P = 2^S masked, bf16; atomic row sums -> lsum
//      3 = O = (P*V) * 1/lvec[row], f32
template <int EPI>
__global__ __launch_bounds__(512, 2) void k_gemm(
    const unsigned short* __restrict__ A, const unsigned short* __restrict__ Bt,
    void* __restrict__ Cv,
    const float* __restrict__ bias_q, const float* __restrict__ bias_k,
    const float* __restrict__ bias_v,
    const float* __restrict__ lvec, float* __restrict__ lsum,
    const int* __restrict__ mask,
    long aZ, long bZ, int ldA, int ldB, int kIters)
{
  // Single contiguous 128KB LDS block. A-buffers at [0, 32768) ushorts,
  // B-buffers at [32768, 65536). One buffer = 256x64 bf16 = 16384 ushorts;
  // BUF stride 16384. Epilogue reuses the whole block as 8 x 16KB wave slices.
  __shared__ __attribute__((aligned(16))) unsigned short LDSu[4 * 256 * 64];
  unsigned short* const AsF = LDSu;
  unsigned short* const BsF = LDSu + 2 * 256 * 64;
  const int tid = threadIdx.x, w = tid >> 6, l = tid & 63;
  const int quad = l >> 4, l15 = l & 15;
  const int wr = w & 1, wc = w >> 1;           // 2M x 4N wave grid
  const int wm = wr * 128, wn = wc * 64;

  // ---- bijective rect XCD swizzle (EPI2: 4x2 rects/z; EPI3: 2x2) ----
  // XCD = dispatch_linear % 8 (round-robin). Co-locate panel sharers.
  int bx = blockIdx.x, by = blockIdx.y, bz = blockIdx.z;
  if constexpr (EPI == 2) {              // grid (8,8,8)
    int lin = bx + (by << 3) + (bz << 6);
    int xcd = lin & 7, slot = lin >> 3;  // 8 blocks per xcd per z
    bx = ((xcd & 1) << 2) + (slot & 3);
    by = ((xcd >> 1) << 1) + ((slot >> 2) & 1);
    bz = slot >> 3;
  } else if constexpr (EPI == 3) {       // grid (8,4,8)
    int lin = bx + (by << 3) + (bz << 5);
    int xcd = lin & 7, slot = lin >> 3;  // 4 blocks per xcd per z
    bx = ((xcd & 3) << 1) + (slot & 1);
    by = ((xcd >> 2) << 1) + ((slot >> 1) & 1);
    bz = slot >> 2;
  }
  const int m0 = bx * 256;
  const int z = bz;

  int n0, sel = 0;
  if constexpr (EPI == 4) { sel = by >> 2; n0 = (by & 3) * 256; }
  else n0 = by * 256;

  const unsigned short* Az = A + (size_t)z * aZ;
  const unsigned short* Bz = (EPI == 4) ? (Bt + ((size_t)sel << 20))
                                        : (Bt + (size_t)z * bZ);

  // ---- hoisted stage streams: per-lane swizzled global addrs + LDS offsets ----
  const int lr = l >> 3, uu = (l & 7) ^ lr;    // stage swizzle (row bases %8==0)
  const unsigned short* gA[2][2]; const unsigned short* gB[2][2];
  int dA[2][2], dB[2][2];
#pragma unroll
  for (int q = 0; q < 2; ++q)
#pragma unroll
    for (int j = 0; j < 2; ++j) {
      int slot = w * 2 + j;
      int rA = (slot >> 3) * 128 + q * 64 + (slot & 7) * 8;
      int rB = (slot >> 2) * 64 + q * 32 + (slot & 3) * 8;
      gA[q][j] = Az + (size_t)(m0 + rA + lr) * ldA + uu * 8;
      gB[q][j] = Bz + (size_t)(n0 + rB + lr) * ldB + uu * 8;
      dA[q][j] = rA * 64; dB[q][j] = rB * 64;
    }

  // ---- hoisted fragment-read byte offsets (frag swizzle (rr&7)==l15&7) ----
  const int cc0 = quad ^ (l15 & 7), cc1 = cc0 ^ 4;
  const int aoffA0 = (wm + l15) * 128 + cc0 * 16;
  const int aoffA1 = (wm + l15) * 128 + cc1 * 16;
  const int aoffB0 = (wn + l15) * 128 + cc0 * 16;
  const int aoffB1 = (wn + l15) * 128 + cc1 * 16;

  floatx4 acc[8][4];
#pragma unroll
  for (int i = 0; i < 8; ++i)
#pragma unroll
    for (int j = 0; j < 4; ++j) { floatx4 zz = {0.f, 0.f, 0.f, 0.f}; acc[i][j] = zz; }

  // -------- prologue: tile0 full + AH0/BH0(1); tile0 guaranteed landed --------
  STAGE_A(0, 0); STAGE_B(0, 0);            // AH0(0), BH0(0)
  STAGE_A(1, 0); STAGE_B(1, 0);            // AH1(0), BH1(0)
  if (kIters > 1) {
    STAGE_A(0, 16384); STAGE_B(0, 16384);  // AH0(1), BH0(1)
    WAITV4;
  } else {
    WAITV0;
  }
  SBAR;

  // -------- main loop: 2 merged phases/K-tile, vmcnt(4)@P34 only ----
#pragma unroll 2
  for (int kt = 0; kt < kIters; ++kt) {
    const int ob = (kt & 1) ? 16384 : 0;   // current buffer (ushort offset)
    const int on = ob ^ 16384;             // next buffer
    const char* pA0 = (const char*)(AsF + ob) + aoffA0;
    const char* pA1 = (const char*)(AsF + ob) + aoffA1;
    const char* pB0 = (const char*)(BsF + ob) + aoffB0;
    const char* pB1 = (const char*)(BsF + ob) + aoffB1;
    bf16x8 af[2][4], bfr0[2][2], bfr1[2][2];

    // ---- P12: Q(0,0)+Q(0,1). reads A0+B0+B1 (16); stage AH1,BH1(t+1)->bn ----
    READ_A(0); READ_B(bfr0, 0); READ_B(bfr1, 1);
    if (kt + 1 < kIters) { STAGE_A(1, on); STAGE_B(1, on); }
    SBAR;
    PRIO1;
    MFMA_Q(0, 0, bfr0);
    MFMA_Q(0, 1, bfr1);
    PRIO0;
    SBAR;
    // ---- P34: Q(1,1)+Q(1,0). reads A1 (8); stage AH0,BH0(t+2)->bc ----
    READ_A(1);
    if (kt + 2 < kIters) { STAGE_A(0, ob); STAGE_B(0, ob); }
    SBAR;
    PRIO1;
    MFMA_Q(1, 1, bfr1);
    MFMA_Q(1, 0, bfr0);
    PRIO0;
    if (kt + 2 < kIters) { WAITV4; } else { WAITV0; }
    SBAR;
  }

  // ---- epilogues. C/D layout col = lane&15, row = quad*4 + reg  [m89/m91].
  // After the final SBAR all LDS reads are retired (last-tile reads are
  // lgkm-gated before their MFMAs, which precede the final barrier) -> LDSu
  // is dead; each wave privately restages its output slice at LDSu + w*8192
  // (16KB) for packed, 16B-coalesced global stores. No cross-wave hazard.
  if constexpr (EPI == 4) {
    unsigned short* C = (unsigned short*)Cv + ((size_t)sel << 24);
    const float* bs = sel == 0 ? bias_q : (sel == 1 ? bias_k : bias_v);
    unsigned short* sl = LDSu + w * 8192;
    if (sel < 2) {
      // slice [128 rows(m)][64 cols(n)] ushorts
      float sc = sel == 0 ? 0.045084439f : 1.0f;   // log2e/32
#pragma unroll
      for (int ns = 0; ns < 4; ++ns) {
        int n_g = n0 + wn + ns * 16 + l15;
        float bv = bs[n_g];
#pragma unroll
        for (int ms = 0; ms < 8; ++ms) {
          int lrow = ms * 16 + quad * 4;
#pragma unroll
          for (int r = 0; r < 4; ++r)
            sl[(lrow + r) * 64 + ns * 16 + l15] = f2bf((acc[ms][ns][r] + bv) * sc);
        }
      }
#pragma unroll
      for (int i = 0; i < 16; ++i) {
        bf16x8 v = *(const bf16x8*)&sl[i * 512 + l * 8];
        *(bf16x8*)&C[(size_t)(m0 + wm + i * 8 + lr) * 1024 + n0 + wn + (l & 7) * 8] = v;
      }
    } else {
      // Vt slice [64 rows(d-local)][128 cols(key-local)] ushorts; the 4
      // r-values are consecutive keys -> packed 8B ds_writes.
#pragma unroll
      for (int ns = 0; ns < 4; ++ns) {
        int n_g = n0 + wn + ns * 16 + l15;
        float bv = bs[n_g];
#pragma unroll
        for (int ms = 0; ms < 8; ++ms) {
          ushort4 pk;
          pk.x = f2bf(acc[ms][ns][0] + bv);
          pk.y = f2bf(acc[ms][ns][1] + bv);
          pk.z = f2bf(acc[ms][ns][2] + bv);
          pk.w = f2bf(acc[ms][ns][3] + bv);
          *(ushort4*)&sl[(ns * 16 + l15) * 128 + ms * 16 + quad * 4] = pk;
        }
      }
      // Vt[b][d][k]: b = m0>>11 (block never crosses batch), d = n-row,
      // key = (m0&2047) + wm + key-local
      const size_t vbase = ((size_t)(m0 >> 11) << 21) + (size_t)((m0 & 2047) + wm);
#pragma unroll
      for (int i = 0; i < 16; ++i) {
        bf16x8 v = *(const bf16x8*)&sl[i * 512 + l * 8];
        int drow = n0 + wn + i * 4 + quad;
        *(bf16x8*)&C[vbase + ((size_t)drow << 11) + (l & 15) * 8] = v;
      }
    }
  } else if constexpr (EPI == 2) {
    // P = 2^S (S pre-scaled by log2e; max-free: |S| small), masked; rowsums.
    unsigned short* C = (unsigned short*)Cv + (size_t)z * 4194304;
    const int* mz = mask + z * 2048;
    unsigned short* sl = LDSu + w * 8192;  // slice [128 m][64 n] ushorts
    float rowsum[8][4];
#pragma unroll
    for (int ms = 0; ms < 8; ++ms)
#pragma unroll
      for (int r = 0; r < 4; ++r) rowsum[ms][r] = 0.f;
#pragma unroll
    for (int ns = 0; ns < 4; ++ns) {
      int n_g = n0 + wn + ns * 16 + l15;
      int mv = mz[n_g];
#pragma unroll
      for (int ms = 0; ms < 8; ++ms) {
        int lrow = ms * 16 + quad * 4;
#pragma unroll
        for (int r = 0; r < 4; ++r) {
          float e;
          asm("v_exp_f32 %0, %1" : "=v"(e) : "v"(acc[ms][ns][r]));  // 2^x
          e = mv ? e : 0.f;
          unsigned short pb = f2bf(e);
          sl[(lrow + r) * 64 + ns * 16 + l15] = pb;
          rowsum[ms][r] += bf2f(pb);
        }
      }
    }
#pragma unroll
    for (int ms = 0; ms < 8; ++ms) {
#pragma unroll
      for (int r = 0; r < 4; ++r) {
        float s = rowsum[ms][r];
#pragma unroll
        for (int off = 1; off < 16; off <<= 1) s += __shfl_xor(s, off);
        if (l15 == 0) {
          int m_g = m0 + wm + ms * 16 + quad * 4 + r;
          atomicAdd(&lsum[z * 2048 + m_g], s);
        }
      }
    }
#pragma unroll
    for (int i = 0; i < 16; ++i) {
      bf16x8 v = *(const bf16x8*)&sl[i * 512 + l * 8];
      *(bf16x8*)&C[(size_t)(m0 + wm + i * 8 + lr) * 2048 + n0 + wn + (l & 7) * 8] = v;
    }
  } else {  // EPI == 3: O = (P*V)/l  (f32 stores already 64B-segment coalesced)
    float* C = (float*)Cv + (size_t)z * 2048 * 1024;
    const float* lz = lvec + z * 2048;
#pragma unroll
    for (int ms = 0; ms < 8; ++ms) {
#pragma unroll
      for (int r = 0; r < 4; ++r) {
        int m_g = m0 + wm + ms * 16 + quad * 4 + r;
        float lw = lz[m_g];
        float inv = lw > 0.f ? 1.f / lw : 0.f;
#pragma unroll
        for (int ns = 0; ns < 4; ++ns) {
          int n_g = n0 + wn + ns * 16 + l15;
          C[(size_t)m_g * 1024 + n_g] = acc[ms][ns][r] * inv;
        }
      }
    }
  }
}

extern "C" void kernel_launch(void* const* d_in, const int* in_sizes, int n_in,
                              void* d_out, int out_size, void* d_ws, size_t ws_size,
                              hipStream_t stream) {
  const float* X    = (const float*)d_in[0];
  const int*   mask = (const int*)d_in[1];
  const float* Wq   = (const float*)d_in[2];
  const float* bq   = (const float*)d_in[3];
  const float* Wk   = (const float*)d_in[4];
  const float* bk   = (const float*)d_in[5];
  const float* Wv   = (const float*)d_in[6];
  const float* bv   = (const float*)d_in[7];
  float* out = (float*)d_out;

  constexpr size_t SZ = (size_t)16384 * 1024;
  unsigned short* Q    = (unsigned short*)d_ws;      // Q|K|Vt contiguous (sel<<24)
  float*          lvec = (float*)(Q + 3 * SZ);
  unsigned short* P    = (unsigned short*)(lvec + 16384);
  unsigned short* Xb   = P;               // overlaid: dead before P written
  unsigned short* Wt   = Xb + SZ;         // 3 x [1024][1024] bf16
  unsigned short* Vt   = Q + 2 * SZ;

  // 1. prep: X->bf16, W->Wt (bf16, transposed), lvec=0
  k_prep<<<dim3(17153), 256, 0, stream>>>(X, Xb, Wq, Wk, Wv, Wt, lvec);

  // 2. fused QKV projection (12 n-strips: 4 Q, 4 K, 4 V)
  k_gemm<4><<<dim3(64, 12, 1), 512, 0, stream>>>(
      Xb, Wt, (void*)Q, bq, bk, bv, nullptr, nullptr, nullptr,
      0, 0, 1024, 1024, 16);

  // 3. P = 2^(Q K^T * log2e/32) masked + atomic row sums
  k_gemm<2><<<dim3(8, 8, 8), 512, 0, stream>>>(
      Q, Q + SZ, (void*)P, nullptr, nullptr, nullptr, nullptr, lvec, mask,
      2048 * 1024, 2048 * 1024, 1024, 1024, 16);

  // 4. O = (P V) / l  -> fp32 out
  k_gemm<3><<<dim3(8, 4, 8), 512, 0, stream>>>(
      P, Vt, (void*)out, nullptr, nullptr, nullptr, lvec, nullptr, nullptr,
      2048 * 2048, 1024 * 2048, 2048, 2048, 32);
}

// Round 10
// 370.347 us; speedup vs baseline: 1.9578x; 1.0219x over previous
//
#include <hip/hip_runtime.h>
#include <stdint.h>

#define DEVI __device__ __forceinline__

typedef __bf16 bf16x8 __attribute__((ext_vector_type(8)));
typedef float  floatx4 __attribute__((ext_vector_type(4)));

// B=8, S=2048, H=1024. M = B*S = 16384.
// ws: Q @0 (32MiB, pre-scaled log2e/32) | K @+32M | Vt @+64M ([8][1024 d][2048 k])
//     lvec @+96M (f32[16384]) | P @+96M+64K (bf16 [8][2048][2048]);
//     P region overlays Xb (32MiB) + Wt (6MiB), dead before P written.
//
// Round-15 = round-9 base (378.5us best) + epilogue bank-conflict fixes.
// r9 counters: WRITE ideal (96MB QKV) but SQ_LDS_BANK_CONFLICT 4.98M — the
// restage SCALAR WRITES collide (slice rows wrap 32 banks exactly: Q/K/P
// 4-way, Vt 16-way). Reads are contiguous per 8-lane group = conflict-free.
// Fix: physical 16B chunk = logical ^ (row&7 / row&15) on BOTH write and
// read sides -> retrieved logical chunk (and all global addresses) unchanged;
// write conflicts drop to 2-way-same-word (free). Also restage EPI3's f32
// output (was direct 64B-segment scalar stores, ~165MB vs 64 ideal): two
// 16KB halves per wave, XOR-chunked, float4 stores in 256B runs.
// K-loop UNTOUCHED from r5/r9 (2 merged phases/K-tile, vmcnt(4)@P34; r6/r7
// perturbations regressed — do not touch phases/waits/register liveness).
// (Kept: no 32x32 MFMA, no B-direct loads; Q carries log2e/32 -> v_exp_f32.)

DEVI unsigned short f2bf(float f) {
  union { float f; uint32_t u; } x; x.f = f;
  return (unsigned short)((x.u + 0x7fffu + ((x.u >> 16) & 1u)) >> 16);
}
DEVI float bf2f(unsigned short s) {
  union { uint32_t u; float f; } x; x.u = ((uint32_t)s) << 16;
  return x.f;
}

// ---------------- fused prep: X->bf16, 3x W transpose->bf16, lvec=0 ----------------
__global__ __launch_bounds__(256) void k_prep(
    const float* __restrict__ X, unsigned short* __restrict__ Xb,
    const float* __restrict__ Wq, const float* __restrict__ Wk,
    const float* __restrict__ Wv, unsigned short* __restrict__ Wt,
    float* __restrict__ lvec) {
  __shared__ float tile[64][65];
  int bx = blockIdx.x, t = threadIdx.x;
  if (bx < 16384) {                 // convert X: 4194304 float4 groups
    int i = bx * 256 + t;
    float4 v = ((const float4*)X)[i];
    ushort4 o;
    o.x = f2bf(v.x); o.y = f2bf(v.y); o.z = f2bf(v.z); o.w = f2bf(v.w);
    ((ushort4*)Xb)[i] = o;
  } else if (bx < 17152) {          // 3 x 256 transpose blocks
    int idx = bx - 16384;
    int sel = idx >> 8, b2 = idx & 255;
    const float* W = sel == 0 ? Wq : (sel == 1 ? Wk : Wv);
    unsigned short* Wo = Wt + ((size_t)sel << 20);
    int h0 = (b2 & 15) * 64, d0 = (b2 >> 4) * 64;
#pragma unroll
    for (int i = 0; i < 16; ++i) {
      int idx2 = i * 256 + t; int r = idx2 >> 6, c = idx2 & 63;
      tile[r][c] = W[(size_t)(h0 + r) * 1024 + d0 + c];
    }
    __syncthreads();
#pragma unroll
    for (int i = 0; i < 16; ++i) {
      int idx2 = i * 256 + t; int r = idx2 >> 6, c = idx2 & 63;
      Wo[(size_t)(d0 + r) * 1024 + h0 + c] = f2bf(tile[c][r]);
    }
  } else {                          // zero lvec (16384 f32)
    float4 z4 = {0.f, 0.f, 0.f, 0.f};
#pragma unroll
    for (int i = 0; i < 16; ++i) ((float4*)lvec)[i * 256 + t] = z4;
  }
}

// ---------------- async 16B global -> LDS ----------------
DEVI void gl_lds16(const unsigned short* gp, const unsigned short* lp) {
  __builtin_amdgcn_global_load_lds(
      (const __attribute__((address_space(1))) void*)gp,
      (__attribute__((address_space(3))) void*)lp, 16, 0, 0);
}

// Stage one half-tile from persistent streams; advance streams +128B (+1 K-tile).
#define STAGE_A(q, BUF)                                                       \
  do {                                                                        \
    gl_lds16(gA[q][0], AsF + (BUF) + dA[q][0]);                               \
    gl_lds16(gA[q][1], AsF + (BUF) + dA[q][1]);                               \
    gA[q][0] += 64; gA[q][1] += 64;                                           \
  } while (0)
#define STAGE_B(q, BUF)                                                       \
  do {                                                                        \
    gl_lds16(gB[q][0], BsF + (BUF) + dB[q][0]);                               \
    gl_lds16(gB[q][1], BsF + (BUF) + dB[q][1]);                               \
    gB[q][0] += 64; gB[q][1] += 64;                                           \
  } while (0)

// Fragment loads: base ptr + compile-time immediate only.
#define READ_A(MH)                                                            \
  _Pragma("unroll") for (int ms = 0; ms < 4; ++ms) {                          \
    af[0][ms] = *(const bf16x8*)(pA0 + (MH) * 8192 + ms * 2048);              \
    af[1][ms] = *(const bf16x8*)(pA1 + (MH) * 8192 + ms * 2048);              \
  }
#define READ_B(DST, NH)                                                       \
  _Pragma("unroll") for (int ns = 0; ns < 2; ++ns) {                          \
    DST[0][ns] = *(const bf16x8*)(pB0 + (NH) * 4096 + ns * 2048);             \
    DST[1][ns] = *(const bf16x8*)(pB1 + (NH) * 4096 + ns * 2048);             \
  }

// 16 MFMAs for one C-quadrant (no setprio; caller wraps the cluster).
#define MFMA_Q(MH, NH, BSET)                                                  \
  _Pragma("unroll") for (int kk = 0; kk < 2; ++kk)                            \
  _Pragma("unroll") for (int ms = 0; ms < 4; ++ms)                            \
  _Pragma("unroll") for (int ns = 0; ns < 2; ++ns)                            \
    acc[(MH) * 4 + ms][(NH) * 2 + ns] =                                       \
        __builtin_amdgcn_mfma_f32_16x16x32_bf16(                              \
            af[kk][ms], BSET[kk][ns], acc[(MH) * 4 + ms][(NH) * 2 + ns],      \
            0, 0, 0);

#define PRIO1 __builtin_amdgcn_s_setprio(1)
#define PRIO0 __builtin_amdgcn_s_setprio(0)
#define WAITV4 asm volatile("s_waitcnt vmcnt(4)" ::: "memory")
#define WAITV0 asm volatile("s_waitcnt vmcnt(0)" ::: "memory")
#define SBAR __builtin_amdgcn_s_barrier()

// ---------------- C = A * Bt^T  (both bf16 row-major, K-major rows) ----------------
// 256x256 tile, BK=64, 8 waves (2M x 4N, 128x64 each), 128KiB dbuf LDS.
// EPI: 4 = fused QKV (sel=blockIdx.y>>2): Q (x+b)*log2e/32, K x+b, V -> Vt[b][d][k]
//      2 = P = 2^S masked, bf16; atomic row sums -> lsum
//      3 = O = (P*V) * 1/lvec[row], f32
template <int EPI>
__global__ __launch_bounds__(512, 2) void k_gemm(
    const unsigned short* __restrict__ A, const unsigned short* __restrict__ Bt,
    void* __restrict__ Cv,
    const float* __restrict__ bias_q, const float* __restrict__ bias_k,
    const float* __restrict__ bias_v,
    const float* __restrict__ lvec, float* __restrict__ lsum,
    const int* __restrict__ mask,
    long aZ, long bZ, int ldA, int ldB, int kIters)
{
  // Single contiguous 128KB LDS block. A-buffers at [0, 32768) ushorts,
  // B-buffers at [32768, 65536). One buffer = 256x64 bf16 = 16384 ushorts;
  // BUF stride 16384. Epilogue reuses the block as 8 x 16KB wave slices.
  __shared__ __attribute__((aligned(16))) unsigned short LDSu[4 * 256 * 64];
  unsigned short* const AsF = LDSu;
  unsigned short* const BsF = LDSu + 2 * 256 * 64;
  const int tid = threadIdx.x, w = tid >> 6, l = tid & 63;
  const int quad = l >> 4, l15 = l & 15;
  const int wr = w & 1, wc = w >> 1;           // 2M x 4N wave grid
  const int wm = wr * 128, wn = wc * 64;

  // ---- bijective rect XCD swizzle (EPI2: 4x2 rects/z; EPI3: 2x2) ----
  int bx = blockIdx.x, by = blockIdx.y, bz = blockIdx.z;
  if constexpr (EPI == 2) {              // grid (8,8,8)
    int lin = bx + (by << 3) + (bz << 6);
    int xcd = lin & 7, slot = lin >> 3;  // 8 blocks per xcd per z
    bx = ((xcd & 1) << 2) + (slot & 3);
    by = ((xcd >> 1) << 1) + ((slot >> 2) & 1);
    bz = slot >> 3;
  } else if constexpr (EPI == 3) {       // grid (8,4,8)
    int lin = bx + (by << 3) + (bz << 5);
    int xcd = lin & 7, slot = lin >> 3;  // 4 blocks per xcd per z
    bx = ((xcd & 3) << 1) + (slot & 1);
    by = ((xcd >> 2) << 1) + ((slot >> 1) & 1);
    bz = slot >> 2;
  }
  const int m0 = bx * 256;
  const int z = bz;

  int n0, sel = 0;
  if constexpr (EPI == 4) { sel = by >> 2; n0 = (by & 3) * 256; }
  else n0 = by * 256;

  const unsigned short* Az = A + (size_t)z * aZ;
  const unsigned short* Bz = (EPI == 4) ? (Bt + ((size_t)sel << 20))
                                        : (Bt + (size_t)z * bZ);

  // ---- hoisted stage streams: per-lane swizzled global addrs + LDS offsets ----
  const int lr = l >> 3, uu = (l & 7) ^ lr;    // stage swizzle (row bases %8==0)
  const unsigned short* gA[2][2]; const unsigned short* gB[2][2];
  int dA[2][2], dB[2][2];
#pragma unroll
  for (int q = 0; q < 2; ++q)
#pragma unroll
    for (int j = 0; j < 2; ++j) {
      int slot = w * 2 + j;
      int rA = (slot >> 3) * 128 + q * 64 + (slot & 7) * 8;
      int rB = (slot >> 2) * 64 + q * 32 + (slot & 3) * 8;
      gA[q][j] = Az + (size_t)(m0 + rA + lr) * ldA + uu * 8;
      gB[q][j] = Bz + (size_t)(n0 + rB + lr) * ldB + uu * 8;
      dA[q][j] = rA * 64; dB[q][j] = rB * 64;
    }

  // ---- hoisted fragment-read byte offsets (frag swizzle (rr&7)==l15&7) ----
  const int cc0 = quad ^ (l15 & 7), cc1 = cc0 ^ 4;
  const int aoffA0 = (wm + l15) * 128 + cc0 * 16;
  const int aoffA1 = (wm + l15) * 128 + cc1 * 16;
  const int aoffB0 = (wn + l15) * 128 + cc0 * 16;
  const int aoffB1 = (wn + l15) * 128 + cc1 * 16;

  floatx4 acc[8][4];
#pragma unroll
  for (int i = 0; i < 8; ++i)
#pragma unroll
    for (int j = 0; j < 4; ++j) { floatx4 zz = {0.f, 0.f, 0.f, 0.f}; acc[i][j] = zz; }

  // -------- prologue: tile0 full + AH0/BH0(1); tile0 guaranteed landed --------
  STAGE_A(0, 0); STAGE_B(0, 0);            // AH0(0), BH0(0)
  STAGE_A(1, 0); STAGE_B(1, 0);            // AH1(0), BH1(0)
  if (kIters > 1) {
    STAGE_A(0, 16384); STAGE_B(0, 16384);  // AH0(1), BH0(1)
    WAITV4;
  } else {
    WAITV0;
  }
  SBAR;

  // -------- main loop: 2 merged phases/K-tile, vmcnt(4)@P34 only ----
#pragma unroll 2
  for (int kt = 0; kt < kIters; ++kt) {
    const int ob = (kt & 1) ? 16384 : 0;   // current buffer (ushort offset)
    const int on = ob ^ 16384;             // next buffer
    const char* pA0 = (const char*)(AsF + ob) + aoffA0;
    const char* pA1 = (const char*)(AsF + ob) + aoffA1;
    const char* pB0 = (const char*)(BsF + ob) + aoffB0;
    const char* pB1 = (const char*)(BsF + ob) + aoffB1;
    bf16x8 af[2][4], bfr0[2][2], bfr1[2][2];

    // ---- P12: Q(0,0)+Q(0,1). reads A0+B0+B1 (16); stage AH1,BH1(t+1)->bn ----
    READ_A(0); READ_B(bfr0, 0); READ_B(bfr1, 1);
    if (kt + 1 < kIters) { STAGE_A(1, on); STAGE_B(1, on); }
    SBAR;
    PRIO1;
    MFMA_Q(0, 0, bfr0);
    MFMA_Q(0, 1, bfr1);
    PRIO0;
    SBAR;
    // ---- P34: Q(1,1)+Q(1,0). reads A1 (8); stage AH0,BH0(t+2)->bc ----
    READ_A(1);
    if (kt + 2 < kIters) { STAGE_A(0, ob); STAGE_B(0, ob); }
    SBAR;
    PRIO1;
    MFMA_Q(1, 1, bfr1);
    MFMA_Q(1, 0, bfr0);
    PRIO0;
    if (kt + 2 < kIters) { WAITV4; } else { WAITV0; }
    SBAR;
  }

  // ---- epilogues. C/D layout col = lane&15, row = quad*4 + reg  [m89/m91].
  // After the final SBAR all LDS reads are retired -> LDSu dead; each wave
  // restages its output in its private 16KB slice (LDSu + w*8192 ushorts).
  // All slice layouts use row-XOR chunk placement: physical 16B-chunk =
  // logical ^ (row&7 / row&15); reads apply the same XOR, so global
  // addressing is unchanged while scalar-write bank conflicts drop to
  // 2-way-same-word (free). Reads stay conflict-free (full-row coverage
  // per 8/16-lane group).
  if constexpr (EPI == 4) {
    unsigned short* C = (unsigned short*)Cv + ((size_t)sel << 24);
    const float* bs = sel == 0 ? bias_q : (sel == 1 ? bias_k : bias_v);
    unsigned short* sl = LDSu + w * 8192;
    if (sel < 2) {
      // slice [128 rows(m)][64 cols(n)]; 8 chunks/row; XOR arg row&7.
      float sc = sel == 0 ? 0.045084439f : 1.0f;   // log2e/32
#pragma unroll
      for (int ns = 0; ns < 4; ++ns) {
        int n_g = n0 + wn + ns * 16 + l15;
        float bv = bs[n_g];
        int c8 = ns * 2 + (l15 >> 3);       // logical chunk of col ns*16+l15
#pragma unroll
        for (int ms = 0; ms < 8; ++ms) {
#pragma unroll
          for (int r = 0; r < 4; ++r) {
            int row = ms * 16 + quad * 4 + r;
            int ph = c8 ^ (row & 7);
            sl[row * 64 + ph * 8 + (l15 & 7)] = f2bf((acc[ms][ns][r] + bv) * sc);
          }
        }
      }
#pragma unroll
      for (int i = 0; i < 16; ++i) {
        int row = i * 8 + lr;
        bf16x8 v = *(const bf16x8*)&sl[row * 64 + ((l & 7) ^ lr) * 8];
        *(bf16x8*)&C[(size_t)(m0 + wm + row) * 1024 + n0 + wn + (l & 7) * 8] = v;
      }
    } else {
      // Vt slice [64 rows(d)][128 cols(key)]; 16 chunks/row; XOR arg row&15
      // (= l15 on write). ushort4 = half-chunk, offset (quad&1)*4.
#pragma unroll
      for (int ns = 0; ns < 4; ++ns) {
        int n_g = n0 + wn + ns * 16 + l15;
        float bv = bs[n_g];
        int row = ns * 16 + l15;
#pragma unroll
        for (int ms = 0; ms < 8; ++ms) {
          ushort4 pk;
          pk.x = f2bf(acc[ms][ns][0] + bv);
          pk.y = f2bf(acc[ms][ns][1] + bv);
          pk.z = f2bf(acc[ms][ns][2] + bv);
          pk.w = f2bf(acc[ms][ns][3] + bv);
          int ph = (ms * 2 + (quad >> 1)) ^ l15;   // ^(row&15), row&15==l15
          *(ushort4*)&sl[row * 128 + ph * 8 + (quad & 1) * 4] = pk;
        }
      }
      const size_t vbase = ((size_t)(m0 >> 11) << 21) + (size_t)((m0 & 2047) + wm);
#pragma unroll
      for (int i = 0; i < 16; ++i) {
        int row = i * 4 + quad;
        int ph = (l & 15) ^ (row & 15);
        bf16x8 v = *(const bf16x8*)&sl[row * 128 + ph * 8];
        int drow = n0 + wn + row;
        *(bf16x8*)&C[vbase + ((size_t)drow << 11) + (l & 15) * 8] = v;
      }
    }
  } else if constexpr (EPI == 2) {
    // P = 2^S (S pre-scaled by log2e; max-free), masked; atomic rowsums.
    unsigned short* C = (unsigned short*)Cv + (size_t)z * 4194304;
    const int* mz = mask + z * 2048;
    unsigned short* sl = LDSu + w * 8192;  // slice [128 m][64 n], XOR row&7
    float rowsum[8][4];
#pragma unroll
    for (int ms = 0; ms < 8; ++ms)
#pragma unroll
      for (int r = 0; r < 4; ++r) rowsum[ms][r] = 0.f;
#pragma unroll
    for (int ns = 0; ns < 4; ++ns) {
      int n_g = n0 + wn + ns * 16 + l15;
      int mv = mz[n_g];
      int c8 = ns * 2 + (l15 >> 3);
#pragma unroll
      for (int ms = 0; ms < 8; ++ms) {
#pragma unroll
        for (int r = 0; r < 4; ++r) {
          int row = ms * 16 + quad * 4 + r;
          float e;
          asm("v_exp_f32 %0, %1" : "=v"(e) : "v"(acc[ms][ns][r]));  // 2^x
          e = mv ? e : 0.f;
          unsigned short pb = f2bf(e);
          int ph = c8 ^ (row & 7);
          sl[row * 64 + ph * 8 + (l15 & 7)] = pb;
          rowsum[ms][r] += bf2f(pb);
        }
      }
    }
#pragma unroll
    for (int ms = 0; ms < 8; ++ms) {
#pragma unroll
      for (int r = 0; r < 4; ++r) {
        float s = rowsum[ms][r];
#pragma unroll
        for (int off = 1; off < 16; off <<= 1) s += __shfl_xor(s, off);
        if (l15 == 0) {
          int m_g = m0 + wm + ms * 16 + quad * 4 + r;
          atomicAdd(&lsum[z * 2048 + m_g], s);
        }
      }
    }
#pragma unroll
    for (int i = 0; i < 16; ++i) {
      int row = i * 8 + lr;
      bf16x8 v = *(const bf16x8*)&sl[row * 64 + ((l & 7) ^ lr) * 8];
      *(bf16x8*)&C[(size_t)(m0 + wm + row) * 2048 + n0 + wn + (l & 7) * 8] = v;
    }
  } else {  // EPI == 3: O = (P*V)/l, f32 — restaged in two 16KB halves.
    float* C = (float*)Cv + (size_t)z * 2048 * 1024;
    const float* lz = lvec + z * 2048;
    float* slf = (float*)(LDSu) + w * 4096;   // 16KB: [64 rows][64 f32]
#pragma unroll
    for (int half = 0; half < 2; ++half) {
      // write: 16 chunks(4xf32)/row; XOR arg row&15 (= quad*4+r).
#pragma unroll
      for (int ms4 = 0; ms4 < 4; ++ms4) {
        int ms = half * 4 + ms4;
#pragma unroll
        for (int r = 0; r < 4; ++r) {
          int row = ms4 * 16 + quad * 4 + r;
          int m_g = m0 + wm + half * 64 + row;
          float lw = lz[m_g];
          float inv = lw > 0.f ? 1.f / lw : 0.f;
#pragma unroll
          for (int ns = 0; ns < 4; ++ns) {
            int ph = (ns * 4 + (l15 >> 2)) ^ (quad * 4 + r);
            slf[row * 64 + ph * 4 + (l15 & 3)] = acc[ms][ns][r] * inv;
          }
        }
      }
      // read + 16B stores (256B contiguous per 16-lane group)
#pragma unroll
      for (int i = 0; i < 16; ++i) {
        int row = i * 4 + quad;
        int ph = (l & 15) ^ (row & 15);
        floatx4 v = *(const floatx4*)&slf[row * 64 + ph * 4];
        int m_g = m0 + wm + half * 64 + row;
        *(floatx4*)&C[(size_t)m_g * 1024 + n0 + wn + (l & 15) * 4] = v;
      }
    }
  }
}

extern "C" void kernel_launch(void* const* d_in, const int* in_sizes, int n_in,
                              void* d_out, int out_size, void* d_ws, size_t ws_size,
                              hipStream_t stream) {
  const float* X    = (const float*)d_in[0];
  const int*   mask = (const int*)d_in[1];
  const float* Wq   = (const float*)d_in[2];
  const float* bq   = (const float*)d_in[3];
  const float* Wk   = (const float*)d_in[4];
  const float* bk   = (const float*)d_in[5];
  const float* Wv   = (const float*)d_in[6];
  const float* bv   = (const float*)d_in[7];
  float* out = (float*)d_out;

  constexpr size_t SZ = (size_t)16384 * 1024;
  unsigned short* Q    = (unsigned short*)d_ws;      // Q|K|Vt contiguous (sel<<24)
  float*          lvec = (float*)(Q + 3 * SZ);
  unsigned short* P    = (unsigned short*)(lvec + 16384);
  unsigned short* Xb   = P;               // overlaid: dead before P written
  unsigned short* Wt   = Xb + SZ;         // 3 x [1024][1024] bf16
  unsigned short* Vt   = Q + 2 * SZ;

  // 1. prep: X->bf16, W->Wt (bf16, transposed), lvec=0
  k_prep<<<dim3(17153), 256, 0, stream>>>(X, Xb, Wq, Wk, Wv, Wt, lvec);

  // 2. fused QKV projection (12 n-strips: 4 Q, 4 K, 4 V)
  k_gemm<4><<<dim3(64, 12, 1), 512, 0, stream>>>(
      Xb, Wt, (void*)Q, bq, bk, bv, nullptr, nullptr, nullptr,
      0, 0, 1024, 1024, 16);

  // 3. P = 2^(Q K^T * log2e/32) masked + atomic row sums
  k_gemm<2><<<dim3(8, 8, 8), 512, 0, stream>>>(
      Q, Q + SZ, (void*)P, nullptr, nullptr, nullptr, nullptr, lvec, mask,
      2048 * 1024, 2048 * 1024, 1024, 1024, 16);

  // 4. O = (P V) / l  -> fp32 out
  k_gemm<3><<<dim3(8, 4, 8), 512, 0, stream>>>(
      P, Vt, (void*)out, nullptr, nullptr, nullptr, lvec, nullptr, nullptr,
      2048 * 2048, 1024 * 2048, 2048, 2048, 32);
}